// Round 4
// baseline (1363.908 us; speedup 1.0000x reference)
//
#include <hip/hip_runtime.h>
#include <cstdint>
#include <cstddef>

#define M_ROWS 65536
#define N_COLS 1024
#define K_DIM  1024

typedef _Float16 f16x8 __attribute__((ext_vector_type(8)));
typedef float f32x4 __attribute__((ext_vector_type(4)));

// ---------------- prep: scale/bias ----------------
__global__ __launch_bounds__(256) void prep_scale_bias(
    const float* __restrict__ gamma, const float* __restrict__ beta,
    const float* __restrict__ mean, const float* __restrict__ var,
    float* __restrict__ bias, float* __restrict__ scale)
{
  int i = blockIdx.x * 256 + threadIdx.x;
  if (i < N_COLS) {
    float s = gamma[i] * rsqrtf(var[i] + 1e-3f);
    scale[i] = s;
    bias[i] = beta[i] - mean[i] * s;
  }
}

// ---------------- prep: W -> Bp (transposed, scaled, f16, fragment-permuted) ----------------
// Bp chunk layout: 16B chunk index = ((kt*16 + wn)*64 + lane)*8 + kc*4 + fn
// holding Wt[n = wn*64 + fn*16 + li][k = kt*64 + kc*32 + g*8 .. +8], lane = g*16+li.
// => in the GEMM, lane's 16 fragments for one kt are contiguous 128B at Bp + tid*128 + kt*131072.
__global__ __launch_bounds__(256) void prep_bp(
    const float* __restrict__ W, const float* __restrict__ scale,
    char* __restrict__ Bp)
{
  __shared__ float tile[64][68];
  int k0 = blockIdx.x * 64, n0 = blockIdx.y * 64;
  int t = threadIdx.x;
  int kr = t >> 2, q = t & 3;
  #pragma unroll
  for (int j = 0; j < 4; ++j) {
    float4 v = *(const float4*)(W + (size_t)(k0 + kr) * N_COLS + n0 + q * 16 + j * 4);
    *(float4*)(&tile[kr][q * 16 + j * 4]) = v;
  }
  __syncthreads();
  int nr = t >> 2;
  int n = n0 + nr;
  float sn = scale[n];
  __align__(16) _Float16 h[16];
  #pragma unroll
  for (int j = 0; j < 16; ++j)
    h[j] = (_Float16)(tile[q * 16 + j][nr] * sn);   // h[j] = Wt[n][k0+q*16+j]
  int wn = n >> 6, fn = (n >> 4) & 3, li = n & 15;
  #pragma unroll
  for (int c = 0; c < 2; ++c) {
    int k = k0 + q * 16 + c * 8;
    int kidx = k >> 3;
    int g = kidx & 3, kc = (kidx >> 2) & 1, kt = kidx >> 3;
    int lane = g * 16 + li;
    size_t chunk = ((size_t)(kt * 16 + wn) * 64 + lane) * 8 + kc * 4 + fn;
    *(uint4*)(Bp + chunk * 16) = *(const uint4*)(&h[c * 8]);
  }
}

// ---------------- fused: z = (A @ W~ + bias) * priors ; out = sparsemax(z) ----------------
// 1024 threads = 16 waves; block = 32 rows x 1024 cols. Wave wn owns 64-col band.
// acc[2][4] (32 regs) + bf[2][4] (32) keeps total <=128 VGPR => 4 waves/SIMD.
// A: fp32 HBM -> f16 LDS, 2-kt-deep register pipeline, 2 LDS bufs, XOR-swizzled.
// B: L2-resident permuted Bp, one base address per lane, immediate-offset loads.
__global__ __launch_bounds__(1024) void fused_gemm_sparsemax(
    const float* __restrict__ A, const char* __restrict__ Bp,
    const float* __restrict__ bias, const float* __restrict__ priors,
    float* __restrict__ out)
{
  __shared__ char asmem[8192];           // 2 x (32 rows x 64 k x f16) = 2 x 4KB
  __shared__ float red[2][32][16];
  __shared__ float redk[2][32][16];

  const int tid = threadIdx.x;
  const int lane = tid & 63, wn = tid >> 6;
  const int li = lane & 15, g = lane >> 4;
  const int m0 = blockIdx.x * 32;

  f32x4 acc[2][4];
  #pragma unroll
  for (int fm = 0; fm < 2; ++fm)
    #pragma unroll
    for (int fn = 0; fn < 4; ++fn) acc[fm][fn] = (f32x4){0.f, 0.f, 0.f, 0.f};

  // ---- A staging: 1024 threads cover 32x64 fp32 tile, 2 f32/thread ----
  const int arow = tid >> 5;             // 0..31
  const int acol = (tid & 31) * 2;       // 0..62
  const float* aptr = A + (size_t)(m0 + arow) * K_DIM + acol;
  const int awoff = arow * 128 + ((acol * 2) ^ ((arow & 7) << 4));
  const int aswz = (li & 7) << 4;

  auto packA = [&](float2 a, int buf) {
    union { _Float16 h[2]; unsigned u; } p;
    p.h[0] = (_Float16)a.x; p.h[1] = (_Float16)a.y;
    *(unsigned*)(&asmem[buf * 4096 + awoff]) = p.u;
  };

  // ---- B base: one address per lane, contiguous 128B per kt ----
  const char* bkt = Bp + (size_t)tid * 128;

  // prologue: kt0 staged, kt1 in flight
  float2 a_next;
  {
    float2 a0 = *(const float2*)(aptr);
    a_next = *(const float2*)(aptr + 64);
    packA(a0, 0);
  }
  __syncthreads();

  for (int kt = 0; kt < 16; ++kt) {
    const int cur = kt & 1;
    // issue A load for kt+2 (clamped; redundant tail loads are harmless)
    const int ktl = (kt + 2 < 16) ? kt + 2 : 15;
    float2 a_far = *(const float2*)(aptr + ktl * 64);
    // issue all 16 B-fragment loads for this kt (immediate offsets)
    f16x8 bf[2][4];
    #pragma unroll
    for (int kc = 0; kc < 2; ++kc)
      #pragma unroll
      for (int fn = 0; fn < 4; ++fn)
        bf[kc][fn] = *(const f16x8*)(bkt + kc * 64 + fn * 16);
    bkt += 131072;
    // MFMA
    #pragma unroll
    for (int kc = 0; kc < 2; ++kc) {
      const int koff = kc * 64 + g * 16;
      f16x8 af0 = *(const f16x8*)(&asmem[cur * 4096 + li * 128 + (koff ^ aswz)]);
      f16x8 af1 = *(const f16x8*)(&asmem[cur * 4096 + (16 + li) * 128 + (koff ^ aswz)]);
      #pragma unroll
      for (int fn = 0; fn < 4; ++fn) {
        acc[0][fn] = __builtin_amdgcn_mfma_f32_16x16x32_f16(af0, bf[kc][fn], acc[0][fn], 0, 0, 0);
        acc[1][fn] = __builtin_amdgcn_mfma_f32_16x16x32_f16(af1, bf[kc][fn], acc[1][fn], 0, 0, 0);
      }
    }
    // stage A(kt+1) into the other buffer (its load was issued last iteration)
    packA(a_next, cur ^ 1);
    a_next = a_far;
    __syncthreads();
  }

  // ---- epilogue: z = (acc + bias) * priors, in registers ----
  float bv[4];
  #pragma unroll
  for (int fn = 0; fn < 4; ++fn) bv[fn] = bias[wn * 64 + fn * 16 + li];

  #pragma unroll
  for (int fm = 0; fm < 2; ++fm)
    #pragma unroll
    for (int r = 0; r < 4; ++r) {
      const float* pp = priors + (size_t)(m0 + fm * 16 + g * 4 + r) * N_COLS + wn * 64 + li;
      #pragma unroll
      for (int fn = 0; fn < 4; ++fn)
        acc[fm][fn][r] = (acc[fm][fn][r] + bv[fn]) * pp[fn * 16];
    }

  // ---- sparsemax on register-resident z ----
  // stage 1: row max (shfl over li, LDS combine over 16 wave-bands)
  {
    float mx[2][4];
    #pragma unroll
    for (int fm = 0; fm < 2; ++fm)
      #pragma unroll
      for (int r = 0; r < 4; ++r) {
        float m = acc[fm][0][r];
        #pragma unroll
        for (int fn = 1; fn < 4; ++fn) m = fmaxf(m, acc[fm][fn][r]);
        m = fmaxf(m, __shfl_xor(m, 1, 64));
        m = fmaxf(m, __shfl_xor(m, 2, 64));
        m = fmaxf(m, __shfl_xor(m, 4, 64));
        m = fmaxf(m, __shfl_xor(m, 8, 64));
        mx[fm][r] = m;
      }
    if (li == 0) {
      #pragma unroll
      for (int fm = 0; fm < 2; ++fm)
        #pragma unroll
        for (int r = 0; r < 4; ++r)
          red[0][fm * 16 + g * 4 + r][wn] = mx[fm][r];
    }
  }
  __syncthreads();

  float lo[2][4], hi[2][4];
  #pragma unroll
  for (int fm = 0; fm < 2; ++fm)
    #pragma unroll
    for (int r = 0; r < 4; ++r) {
      const float* rr = &red[0][fm * 16 + g * 4 + r][0];
      float4 q0 = *(const float4*)(rr);
      float4 q1 = *(const float4*)(rr + 4);
      float4 q2 = *(const float4*)(rr + 8);
      float4 q3 = *(const float4*)(rr + 12);
      float M = fmaxf(fmaxf(fmaxf(q0.x, q0.y), fmaxf(q0.z, q0.w)),
                      fmaxf(fmaxf(q1.x, q1.y), fmaxf(q1.z, q1.w)));
      M = fmaxf(M, fmaxf(fmaxf(fmaxf(q2.x, q2.y), fmaxf(q2.z, q2.w)),
                         fmaxf(fmaxf(q3.x, q3.y), fmaxf(q3.z, q3.w))));
      lo[fm][r] = M - 1.0f;
      hi[fm][r] = M;
    }

  // stage 2: 12 bisections on f(tau) = sum relu(z - tau) - 1
  float tt[2][4];
  for (int it = 0; it < 12; ++it) {
    const int b = (it + 1) & 1;
    float sv[2][4];
    #pragma unroll
    for (int fm = 0; fm < 2; ++fm)
      #pragma unroll
      for (int r = 0; r < 4; ++r) {
        float t = 0.5f * (lo[fm][r] + hi[fm][r]);
        tt[fm][r] = t;
        float s = 0.f;
        #pragma unroll
        for (int fn = 0; fn < 4; ++fn) s += fmaxf(acc[fm][fn][r] - t, 0.f);
        s += __shfl_xor(s, 1, 64);
        s += __shfl_xor(s, 2, 64);
        s += __shfl_xor(s, 4, 64);
        s += __shfl_xor(s, 8, 64);
        sv[fm][r] = s;
      }
    if (li == 0) {
      #pragma unroll
      for (int fm = 0; fm < 2; ++fm)
        #pragma unroll
        for (int r = 0; r < 4; ++r)
          red[b][fm * 16 + g * 4 + r][wn] = sv[fm][r];
    }
    __syncthreads();
    #pragma unroll
    for (int fm = 0; fm < 2; ++fm)
      #pragma unroll
      for (int r = 0; r < 4; ++r) {
        const float* rr = &red[b][fm * 16 + g * 4 + r][0];
        float4 q0 = *(const float4*)(rr);
        float4 q1 = *(const float4*)(rr + 4);
        float4 q2 = *(const float4*)(rr + 8);
        float4 q3 = *(const float4*)(rr + 12);
        float S = ((q0.x + q0.y) + (q0.z + q0.w)) + ((q1.x + q1.y) + (q1.z + q1.w))
                + ((q2.x + q2.y) + (q2.z + q2.w)) + ((q3.x + q3.y) + (q3.z + q3.w));
        if (S >= 1.f) lo[fm][r] = tt[fm][r]; else hi[fm][r] = tt[fm][r];
      }
  }

  // stage 3: 2 exact Newton polish steps: tau = (sum_{z>tau} z - 1) / k
  float tv[2][4];
  #pragma unroll
  for (int fm = 0; fm < 2; ++fm)
    #pragma unroll
    for (int r = 0; r < 4; ++r) tv[fm][r] = lo[fm][r];

  for (int nit = 0; nit < 2; ++nit) {
    const int b = (nit + 1) & 1;
    float sv[2][4], kv[2][4];
    #pragma unroll
    for (int fm = 0; fm < 2; ++fm)
      #pragma unroll
      for (int r = 0; r < 4; ++r) {
        float s = 0.f, k = 0.f;
        float t = tv[fm][r];
        #pragma unroll
        for (int fn = 0; fn < 4; ++fn) {
          float d = acc[fm][fn][r];
          bool gt = d > t;
          s += gt ? d : 0.f;
          k += gt ? 1.f : 0.f;
        }
        s += __shfl_xor(s, 1, 64); k += __shfl_xor(k, 1, 64);
        s += __shfl_xor(s, 2, 64); k += __shfl_xor(k, 2, 64);
        s += __shfl_xor(s, 4, 64); k += __shfl_xor(k, 4, 64);
        s += __shfl_xor(s, 8, 64); k += __shfl_xor(k, 8, 64);
        sv[fm][r] = s; kv[fm][r] = k;
      }
    if (li == 0) {
      #pragma unroll
      for (int fm = 0; fm < 2; ++fm)
        #pragma unroll
        for (int r = 0; r < 4; ++r) {
          red[b][fm * 16 + g * 4 + r][wn] = sv[fm][r];
          redk[b][fm * 16 + g * 4 + r][wn] = kv[fm][r];
        }
    }
    __syncthreads();
    #pragma unroll
    for (int fm = 0; fm < 2; ++fm)
      #pragma unroll
      for (int r = 0; r < 4; ++r) {
        const float* rr = &red[b][fm * 16 + g * 4 + r][0];
        const float* rk = &redk[b][fm * 16 + g * 4 + r][0];
        float S = 0.f, K = 0.f;
        #pragma unroll
        for (int j = 0; j < 4; ++j) {
          float4 q = *(const float4*)(rr + j * 4);
          float4 qk = *(const float4*)(rk + j * 4);
          S += (q.x + q.y) + (q.z + q.w);
          K += (qk.x + qk.y) + (qk.z + qk.w);
        }
        tv[fm][r] = (S - 1.f) / K;   // K >= 1 (row max stays in support)
      }
  }

  // ---- write out = relu(z - tau) ----
  #pragma unroll
  for (int fm = 0; fm < 2; ++fm)
    #pragma unroll
    for (int r = 0; r < 4; ++r) {
      float* op = out + (size_t)(m0 + fm * 16 + g * 4 + r) * N_COLS + wn * 64 + li;
      float t = tv[fm][r];
      #pragma unroll
      for (int fn = 0; fn < 4; ++fn)
        op[fn * 16] = fmaxf(acc[fm][fn][r] - t, 0.f);
    }
}

// ---------------- launch ----------------
extern "C" void kernel_launch(void* const* d_in, const int* in_sizes, int n_in,
                              void* d_out, int out_size, void* d_ws, size_t ws_size,
                              hipStream_t stream) {
  const float* inputs = (const float*)d_in[0];
  const float* priors = (const float*)d_in[1];
  const float* W      = (const float*)d_in[2];
  const float* gamma  = (const float*)d_in[3];
  const float* beta   = (const float*)d_in[4];
  const float* mean   = (const float*)d_in[5];
  const float* var    = (const float*)d_in[6];
  float* out = (float*)d_out;

  char* ws = (char*)d_ws;
  float* bias  = (float*)ws;                 // 4 KB
  float* scale = (float*)(ws + 4096);        // 4 KB
  char*  Bp    = ws + 8192;                  // 2 MB, fragment-permuted scaled W^T (f16)

  prep_scale_bias<<<4, 256, 0, stream>>>(gamma, beta, mean, var, bias, scale);
  prep_bp<<<dim3(16, 16), 256, 0, stream>>>(W, scale, Bp);
  fused_gemm_sparsemax<<<M_ROWS / 32, 1024, 0, stream>>>(inputs, Bp, bias, priors, out);
}

// Round 5
// 1097.798 us; speedup vs baseline: 1.2424x; 1.2424x over previous
//
#include <hip/hip_runtime.h>
#include <cstdint>
#include <cstddef>

#define M_ROWS 65536
#define N_COLS 1024
#define K_DIM  1024

typedef _Float16 f16x8 __attribute__((ext_vector_type(8)));
typedef float f32x4 __attribute__((ext_vector_type(4)));

// ---------------- prep: scale/bias ----------------
__global__ __launch_bounds__(256) void prep_scale_bias(
    const float* __restrict__ gamma, const float* __restrict__ beta,
    const float* __restrict__ mean, const float* __restrict__ var,
    float* __restrict__ bias, float* __restrict__ scale)
{
  int i = blockIdx.x * 256 + threadIdx.x;
  if (i < N_COLS) {
    float s = gamma[i] * rsqrtf(var[i] + 1e-3f);
    scale[i] = s;
    bias[i] = beta[i] - mean[i] * s;
  }
}

// ---------------- prep: W -> Bp (transposed, scaled, f16, fragment-permuted) ----------------
// Bp chunk layout: 16B chunk index = ((kt*16 + wn)*64 + lane)*8 + kc*4 + fn
// holding Wt[n = wn*64 + fn*16 + li][k = kt*64 + kc*32 + g*8 .. +8], lane = g*16+li.
// => in the GEMM, lane's 16 fragments for one kt are contiguous 128B at Bp + tid*128 + kt*131072.
__global__ __launch_bounds__(256) void prep_bp(
    const float* __restrict__ W, const float* __restrict__ scale,
    char* __restrict__ Bp)
{
  __shared__ float tile[64][68];
  int k0 = blockIdx.x * 64, n0 = blockIdx.y * 64;
  int t = threadIdx.x;
  int kr = t >> 2, q = t & 3;
  #pragma unroll
  for (int j = 0; j < 4; ++j) {
    float4 v = *(const float4*)(W + (size_t)(k0 + kr) * N_COLS + n0 + q * 16 + j * 4);
    *(float4*)(&tile[kr][q * 16 + j * 4]) = v;
  }
  __syncthreads();
  int nr = t >> 2;
  int n = n0 + nr;
  float sn = scale[n];
  __align__(16) _Float16 h[16];
  #pragma unroll
  for (int j = 0; j < 16; ++j)
    h[j] = (_Float16)(tile[q * 16 + j][nr] * sn);   // h[j] = Wt[n][k0+q*16+j]
  int wn = n >> 6, fn = (n >> 4) & 3, li = n & 15;
  #pragma unroll
  for (int c = 0; c < 2; ++c) {
    int k = k0 + q * 16 + c * 8;
    int kidx = k >> 3;
    int g = kidx & 3, kc = (kidx >> 2) & 1, kt = kidx >> 3;
    int lane = g * 16 + li;
    size_t chunk = ((size_t)(kt * 16 + wn) * 64 + lane) * 8 + kc * 4 + fn;
    *(uint4*)(Bp + chunk * 16) = *(const uint4*)(&h[c * 8]);
  }
}

// ---------------- fused: z = (A @ W~ + bias) * priors ; out = sparsemax(z) ----------------
// 1024 threads = 16 waves; block = 32 rows x 1024 cols. Wave wn owns 64-col band.
// __launch_bounds__(1024,4): 16 waves/CU (1 block), VGPR cap 128 -> no spill.
// A: fp32 HBM -> f16 LDS, 2-kt-deep register pipeline, 2 LDS bufs, XOR-swizzled.
// B: L2-resident permuted Bp, one base address per lane, immediate-offset loads.
// Sparsemax: per-wave shfl partials + lean two-level LDS combine (pr -> tot broadcast).
__global__ __launch_bounds__(1024, 4) void fused_gemm_sparsemax(
    const float* __restrict__ A, const char* __restrict__ Bp,
    const float* __restrict__ bias, const float* __restrict__ priors,
    float* __restrict__ out)
{
  __shared__ char asmem[8192];           // 2 x (32 rows x 64 k x f16)
  __shared__ float pr[32][18];           // per-row per-wave partials (padded)
  __shared__ float prk[32][18];          // support-count partials (Newton)
  __shared__ float tot[32];
  __shared__ float totk[32];

  const int tid = threadIdx.x;
  const int lane = tid & 63, wn = tid >> 6;
  const int li = lane & 15, g = lane >> 4;
  const int m0 = blockIdx.x * 32;

  f32x4 acc[2][4];
  #pragma unroll
  for (int fm = 0; fm < 2; ++fm)
    #pragma unroll
    for (int fn = 0; fn < 4; ++fn) acc[fm][fn] = (f32x4){0.f, 0.f, 0.f, 0.f};

  // ---- A staging: 1024 threads cover 32x64 fp32 tile, 2 f32/thread ----
  const int arow = tid >> 5;             // 0..31
  const int acol = (tid & 31) * 2;       // 0..62
  const float* aptr = A + (size_t)(m0 + arow) * K_DIM + acol;
  const int awoff = arow * 128 + ((acol * 2) ^ ((arow & 7) << 4));
  const int aswz = (li & 7) << 4;

  auto packA = [&](float2 a, int buf) {
    union { _Float16 h[2]; unsigned u; } p;
    p.h[0] = (_Float16)a.x; p.h[1] = (_Float16)a.y;
    *(unsigned*)(&asmem[buf * 4096 + awoff]) = p.u;
  };

  // ---- B base: one address per lane, contiguous 128B per kt ----
  const char* bkt = Bp + (size_t)tid * 128;

  // prologue: kt0 staged, kt1 in flight
  float2 a_next;
  {
    float2 a0 = *(const float2*)(aptr);
    a_next = *(const float2*)(aptr + 64);
    packA(a0, 0);
  }
  __syncthreads();

  for (int kt = 0; kt < 16; ++kt) {
    const int cur = kt & 1;
    const int ktl = (kt + 2 < 16) ? kt + 2 : 15;
    float2 a_far = *(const float2*)(aptr + ktl * 64);
    f16x8 bf[2][4];
    #pragma unroll
    for (int kc = 0; kc < 2; ++kc)
      #pragma unroll
      for (int fn = 0; fn < 4; ++fn)
        bf[kc][fn] = *(const f16x8*)(bkt + kc * 64 + fn * 16);
    bkt += 131072;
    #pragma unroll
    for (int kc = 0; kc < 2; ++kc) {
      const int koff = kc * 64 + g * 16;
      f16x8 af0 = *(const f16x8*)(&asmem[cur * 4096 + li * 128 + (koff ^ aswz)]);
      f16x8 af1 = *(const f16x8*)(&asmem[cur * 4096 + (16 + li) * 128 + (koff ^ aswz)]);
      #pragma unroll
      for (int fn = 0; fn < 4; ++fn) {
        acc[0][fn] = __builtin_amdgcn_mfma_f32_16x16x32_f16(af0, bf[kc][fn], acc[0][fn], 0, 0, 0);
        acc[1][fn] = __builtin_amdgcn_mfma_f32_16x16x32_f16(af1, bf[kc][fn], acc[1][fn], 0, 0, 0);
      }
    }
    packA(a_next, cur ^ 1);
    a_next = a_far;
    __syncthreads();
  }

  // ---- epilogue: z = (acc + bias) * priors, in registers ----
  {
    float bv[4];
    #pragma unroll
    for (int fn = 0; fn < 4; ++fn) bv[fn] = bias[wn * 64 + fn * 16 + li];
    #pragma unroll
    for (int fm = 0; fm < 2; ++fm)
      #pragma unroll
      for (int r = 0; r < 4; ++r) {
        const float* pp = priors + (size_t)(m0 + fm * 16 + g * 4 + r) * N_COLS + wn * 64 + li;
        #pragma unroll
        for (int fn = 0; fn < 4; ++fn)
          acc[fm][fn][r] = (acc[fm][fn][r] + bv[fn]) * pp[fn * 16];
      }
  }

  // ---- lean combine helpers ----
  // val[fm][r]: wave-partial (already shfl-reduced over li, identical across the 16 li lanes
  // of each group). Level 2: waves 0-3 reduce 8 rows each; result broadcast via tot[].
  auto combine_sum = [&](float val[2][4], float* res) {
    if (li == 0) {
      #pragma unroll
      for (int fm = 0; fm < 2; ++fm)
        #pragma unroll
        for (int r = 0; r < 4; ++r)
          pr[fm * 16 + g * 4 + r][wn] = val[fm][r];
    }
    __syncthreads();
    if (wn < 4) {
      int row = wn * 8 + (lane >> 3);
      float2 p2 = *(const float2*)(&pr[row][2 * (lane & 7)]);
      float s = p2.x + p2.y;
      s += __shfl_xor(s, 1, 64);
      s += __shfl_xor(s, 2, 64);
      s += __shfl_xor(s, 4, 64);
      if ((lane & 7) == 0) tot[row] = s;
    }
    __syncthreads();
    #pragma unroll
    for (int fm = 0; fm < 2; ++fm)
      #pragma unroll
      for (int r = 0; r < 4; ++r)
        res[fm * 4 + r] = tot[fm * 16 + g * 4 + r];
  };

  // ---- stage 1: row max ----
  float lo[2][4], hi[2][4];
  {
    float mx[2][4];
    #pragma unroll
    for (int fm = 0; fm < 2; ++fm)
      #pragma unroll
      for (int r = 0; r < 4; ++r) {
        float m = acc[fm][0][r];
        #pragma unroll
        for (int fn = 1; fn < 4; ++fn) m = fmaxf(m, acc[fm][fn][r]);
        m = fmaxf(m, __shfl_xor(m, 1, 64));
        m = fmaxf(m, __shfl_xor(m, 2, 64));
        m = fmaxf(m, __shfl_xor(m, 4, 64));
        m = fmaxf(m, __shfl_xor(m, 8, 64));
        mx[fm][r] = m;
      }
    if (li == 0) {
      #pragma unroll
      for (int fm = 0; fm < 2; ++fm)
        #pragma unroll
        for (int r = 0; r < 4; ++r)
          pr[fm * 16 + g * 4 + r][wn] = mx[fm][r];
    }
    __syncthreads();
    if (wn < 4) {
      int row = wn * 8 + (lane >> 3);
      float2 p2 = *(const float2*)(&pr[row][2 * (lane & 7)]);
      float m = fmaxf(p2.x, p2.y);
      m = fmaxf(m, __shfl_xor(m, 1, 64));
      m = fmaxf(m, __shfl_xor(m, 2, 64));
      m = fmaxf(m, __shfl_xor(m, 4, 64));
      if ((lane & 7) == 0) tot[row] = m;
    }
    __syncthreads();
    #pragma unroll
    for (int fm = 0; fm < 2; ++fm)
      #pragma unroll
      for (int r = 0; r < 4; ++r) {
        float M = tot[fm * 16 + g * 4 + r];
        lo[fm][r] = M - 1.0f;
        hi[fm][r] = M;
      }
  }

  // ---- stage 2: 12 bisections on f(tau) = sum relu(z - tau) - 1 ----
  for (int it = 0; it < 12; ++it) {
    float tt[2][4], sv[2][4], Sv[8];
    #pragma unroll
    for (int fm = 0; fm < 2; ++fm)
      #pragma unroll
      for (int r = 0; r < 4; ++r) {
        float t = 0.5f * (lo[fm][r] + hi[fm][r]);
        tt[fm][r] = t;
        float s = 0.f;
        #pragma unroll
        for (int fn = 0; fn < 4; ++fn) s += fmaxf(acc[fm][fn][r] - t, 0.f);
        s += __shfl_xor(s, 1, 64);
        s += __shfl_xor(s, 2, 64);
        s += __shfl_xor(s, 4, 64);
        s += __shfl_xor(s, 8, 64);
        sv[fm][r] = s;
      }
    combine_sum(sv, Sv);
    #pragma unroll
    for (int fm = 0; fm < 2; ++fm)
      #pragma unroll
      for (int r = 0; r < 4; ++r) {
        if (Sv[fm * 4 + r] >= 1.f) lo[fm][r] = tt[fm][r]; else hi[fm][r] = tt[fm][r];
      }
  }

  // ---- stage 3: 2 exact Newton polish steps: tau = (sum_{z>tau} z - 1) / k ----
  float tv[2][4];
  #pragma unroll
  for (int fm = 0; fm < 2; ++fm)
    #pragma unroll
    for (int r = 0; r < 4; ++r) tv[fm][r] = lo[fm][r];

  for (int nit = 0; nit < 2; ++nit) {
    float sv[2][4], kv[2][4];
    #pragma unroll
    for (int fm = 0; fm < 2; ++fm)
      #pragma unroll
      for (int r = 0; r < 4; ++r) {
        float s = 0.f, k = 0.f;
        float t = tv[fm][r];
        #pragma unroll
        for (int fn = 0; fn < 4; ++fn) {
          float d = acc[fm][fn][r];
          bool gt = d > t;
          s += gt ? d : 0.f;
          k += gt ? 1.f : 0.f;
        }
        s += __shfl_xor(s, 1, 64); k += __shfl_xor(k, 1, 64);
        s += __shfl_xor(s, 2, 64); k += __shfl_xor(k, 2, 64);
        s += __shfl_xor(s, 4, 64); k += __shfl_xor(k, 4, 64);
        s += __shfl_xor(s, 8, 64); k += __shfl_xor(k, 8, 64);
        sv[fm][r] = s; kv[fm][r] = k;
      }
    // combined two-array reduce in one barrier pair
    if (li == 0) {
      #pragma unroll
      for (int fm = 0; fm < 2; ++fm)
        #pragma unroll
        for (int r = 0; r < 4; ++r) {
          pr[fm * 16 + g * 4 + r][wn] = sv[fm][r];
          prk[fm * 16 + g * 4 + r][wn] = kv[fm][r];
        }
    }
    __syncthreads();
    if (wn < 4) {
      int row = wn * 8 + (lane >> 3);
      float2 p2 = *(const float2*)(&pr[row][2 * (lane & 7)]);
      float2 q2 = *(const float2*)(&prk[row][2 * (lane & 7)]);
      float s = p2.x + p2.y;
      float k = q2.x + q2.y;
      s += __shfl_xor(s, 1, 64); k += __shfl_xor(k, 1, 64);
      s += __shfl_xor(s, 2, 64); k += __shfl_xor(k, 2, 64);
      s += __shfl_xor(s, 4, 64); k += __shfl_xor(k, 4, 64);
      if ((lane & 7) == 0) { tot[row] = s; totk[row] = k; }
    }
    __syncthreads();
    #pragma unroll
    for (int fm = 0; fm < 2; ++fm)
      #pragma unroll
      for (int r = 0; r < 4; ++r) {
        int row = fm * 16 + g * 4 + r;
        tv[fm][r] = (tot[row] - 1.f) / totk[row];   // k >= 1 (row max stays in support)
      }
  }

  // ---- write out = relu(z - tau) ----
  #pragma unroll
  for (int fm = 0; fm < 2; ++fm)
    #pragma unroll
    for (int r = 0; r < 4; ++r) {
      float* op = out + (size_t)(m0 + fm * 16 + g * 4 + r) * N_COLS + wn * 64 + li;
      float t = tv[fm][r];
      #pragma unroll
      for (int fn = 0; fn < 4; ++fn)
        op[fn * 16] = fmaxf(acc[fm][fn][r] - t, 0.f);
    }
}

// ---------------- launch ----------------
extern "C" void kernel_launch(void* const* d_in, const int* in_sizes, int n_in,
                              void* d_out, int out_size, void* d_ws, size_t ws_size,
                              hipStream_t stream) {
  const float* inputs = (const float*)d_in[0];
  const float* priors = (const float*)d_in[1];
  const float* W      = (const float*)d_in[2];
  const float* gamma  = (const float*)d_in[3];
  const float* beta   = (const float*)d_in[4];
  const float* mean   = (const float*)d_in[5];
  const float* var    = (const float*)d_in[6];
  float* out = (float*)d_out;

  char* ws = (char*)d_ws;
  float* bias  = (float*)ws;                 // 4 KB
  float* scale = (float*)(ws + 4096);        // 4 KB
  char*  Bp    = ws + 8192;                  // 2 MB, fragment-permuted scaled W^T (f16)

  prep_scale_bias<<<4, 256, 0, stream>>>(gamma, beta, mean, var, bias, scale);
  prep_bp<<<dim3(16, 16), 256, 0, stream>>>(W, scale, Bp);
  fused_gemm_sparsemax<<<M_ROWS / 32, 1024, 0, stream>>>(inputs, Bp, bias, priors, out);
}